// Round 7
// baseline (541.918 us; speedup 1.0000x reference)
//
#include <hip/hip_runtime.h>

// GCN, 2 layers, in-dim 1, scalar-per-node propagation (verified R3-R6):
//   deg[c] = 1 + indeg(c); dinv = rsqrt(deg)
//   S[c]   = dinv[c] * ( xd[c] + sum_{(r,c)} xd[r] ),  xd = dinv*x
//   td[r]  = dinv[r] * sum_f relu(b1[f] + W1[f]*S[r]) * W2[f]
//   y[c]   = clip( b2 + dinv[c] * ( td[c] + sum_{(r,c)} td[r] ), -0.5, 9.5 )
//
// R6: consume passes latency-bound (occ 66%, VALU 2.3%, HBM 6%): 1.9
// blocks/CU and serialized vmcnt waits. This round: 4 blocks/bucket
// (980 x 512thr ~ 32 waves/CU) + software-pipelined consume loops
// (prefetch next uint4 across the gather/ds_add group). gpb tiered by
// ws_size: 4 if ~76.4MB fits, else proven 2-partial layout, else R3 path.

#define SZ      2048
#define BSHIFT  11
#define BMASK   2047u
#define ROWBITS 21
#define ROWMASK ((1u << ROWBITS) - 1u)
#define CHUNK   8192

// ---------- phase 1: per-chunk histogram (int4) ----------
__global__ __launch_bounds__(256) void gcn_hist(const int* __restrict__ col,
                                                unsigned* __restrict__ H, int e) {
    __shared__ unsigned h[256];
    int c = blockIdx.x, tid = threadIdx.x;
    int lo = c * CHUNK, hi = min(e, lo + CHUNK);
    h[tid] = 0u;
    __syncthreads();
    int nv = (hi - lo) >> 2;
    const int4* cv = (const int4*)(col + lo);
    for (int k = tid; k < nv; k += 256) {
        int4 v = cv[k];
        atomicAdd(&h[((unsigned)v.x) >> BSHIFT], 1u);
        atomicAdd(&h[((unsigned)v.y) >> BSHIFT], 1u);
        atomicAdd(&h[((unsigned)v.z) >> BSHIFT], 1u);
        atomicAdd(&h[((unsigned)v.w) >> BSHIFT], 1u);
    }
    for (int i = lo + (nv << 2) + tid; i < hi; i += 256)
        atomicAdd(&h[((unsigned)col[i]) >> BSHIFT], 1u);
    __syncthreads();
    H[(size_t)c * 256 + tid] = h[tid];
}

// ---------- phase 2a: per-bucket scan over chunks ----------
__global__ __launch_bounds__(256) void gcn_scan1(unsigned* __restrict__ H,
                                                 unsigned* __restrict__ T, int C) {
    int b = blockIdx.x, tid = threadIdx.x;
    int L = (C + 255) / 256;
    int c0 = tid * L;
    unsigned partial = 0;
    for (int k = 0; k < L; ++k) {
        int c = c0 + k;
        if (c < C) partial += H[(size_t)c * 256 + b];
    }
    __shared__ unsigned s[256];
    s[tid] = partial;
    __syncthreads();
    for (int off = 1; off < 256; off <<= 1) {
        unsigned t = (tid >= off) ? s[tid - off] : 0u;
        __syncthreads();
        s[tid] += t;
        __syncthreads();
    }
    unsigned run = s[tid] - partial;
    for (int k = 0; k < L; ++k) {
        int c = c0 + k;
        if (c < C) {
            unsigned tmp = H[(size_t)c * 256 + b];
            H[(size_t)c * 256 + b] = run;
            run += tmp;
        }
    }
    if (tid == 255) T[b] = s[255];
}

// ---------- phase 2b: bucket-level exclusive scan ----------
__global__ __launch_bounds__(256) void gcn_scan2(const unsigned* __restrict__ T,
                                                 unsigned* __restrict__ S) {
    int tid = threadIdx.x;
    __shared__ unsigned s[256];
    unsigned v = T[tid];
    s[tid] = v;
    __syncthreads();
    for (int off = 1; off < 256; off <<= 1) {
        unsigned t = (tid >= off) ? s[tid - off] : 0u;
        __syncthreads();
        s[tid] += t;
        __syncthreads();
    }
    S[tid] = s[tid] - v;
}

// ---------- phase 3: local bucket-sort + coalesced write ----------
__global__ __launch_bounds__(512) void gcn_reorder(const int* __restrict__ row,
                                                   const int* __restrict__ col,
                                                   const unsigned* __restrict__ H,
                                                   const unsigned* __restrict__ S,
                                                   unsigned* __restrict__ sorted, int e) {
    __shared__ unsigned keys[CHUNK];
    __shared__ unsigned hist[256], scanL[256], cnt[256], baseG[256];
    int c = blockIdx.x, tid = threadIdx.x;
    int lo = c * CHUNK, hi = min(e, lo + CHUNK), m = hi - lo;
    if (tid < 256) { hist[tid] = 0u; cnt[tid] = 0u; }
    __syncthreads();
    for (int i = lo + tid; i < hi; i += 512)
        atomicAdd(&hist[((unsigned)col[i]) >> BSHIFT], 1u);
    __syncthreads();
    if (tid < 256) scanL[tid] = hist[tid];
    __syncthreads();
    for (int off = 1; off < 256; off <<= 1) {
        unsigned t = 0u;
        if (tid < 256 && tid >= off) t = scanL[tid - off];
        __syncthreads();
        if (tid < 256) scanL[tid] += t;
        __syncthreads();
    }
    if (tid < 256) scanL[tid] -= hist[tid];    // exclusive
    __syncthreads();
    for (int i = lo + tid; i < hi; i += 512) {
        unsigned cv = (unsigned)col[i];
        unsigned b = cv >> BSHIFT;
        unsigned r = scanL[b] + atomicAdd(&cnt[b], 1u);
        keys[r] = ((cv & BMASK) << ROWBITS) | (unsigned)row[i];
    }
    if (tid < 256) baseG[tid] = S[tid] + H[(size_t)c * 256 + tid] - scanL[tid];
    __syncthreads();
    for (int j = tid; j < m; j += 512) {
        int lo2 = 0, hi2 = 255;
        #pragma unroll
        for (int it = 0; it < 8; ++it) {
            int mid = (lo2 + hi2 + 1) >> 1;
            if (scanL[mid] <= (unsigned)j) lo2 = mid; else hi2 = mid - 1;
        }
        sorted[baseG[lo2] + j] = keys[j];
    }
}

// ---------- consume: gpb blocks per bucket -> private partials ----------
__global__ __launch_bounds__(1024) void gcn_count(const unsigned* __restrict__ sorted,
                                                  const unsigned* __restrict__ S,
                                                  float* __restrict__ P, int npad, int e,
                                                  int gpb) {
    __shared__ float acc[SZ];
    int b = blockIdx.x / gpb, g = blockIdx.x % gpb, tid = threadIdx.x;
    int bs = blockDim.x;
    for (int i = tid; i < SZ; i += bs) acc[i] = 0.0f;
    __syncthreads();
    int lo = S[b];
    int hi = (b + 1 < 256) ? (int)S[b + 1] : e;
    int q = (hi - lo + gpb - 1) / gpb;
    int mylo = lo + g * q, myhi = min(hi, mylo + q);
    if (mylo > myhi) mylo = myhi;
    int i0 = min((mylo + 3) & ~3, myhi);
    for (int i = mylo + tid; i < i0; i += bs)
        atomicAdd(&acc[sorted[i] >> ROWBITS], 1.0f);
    int nv = (myhi - i0) >> 2;
    const uint4* sv = (const uint4*)(sorted + i0);
    int k = tid;
    if (k < nv) {
        uint4 v = sv[k];
        for (;;) {
            int k2 = k + bs;
            uint4 vn;
            bool more = k2 < nv;
            if (more) vn = sv[k2];           // prefetch overlaps the adds
            atomicAdd(&acc[v.x >> ROWBITS], 1.0f);
            atomicAdd(&acc[v.y >> ROWBITS], 1.0f);
            atomicAdd(&acc[v.z >> ROWBITS], 1.0f);
            atomicAdd(&acc[v.w >> ROWBITS], 1.0f);
            if (!more) break;
            v = vn; k = k2;
        }
    }
    for (int i = i0 + (nv << 2) + tid; i < myhi; i += bs)
        atomicAdd(&acc[sorted[i] >> ROWBITS], 1.0f);
    __syncthreads();
    size_t off = (size_t)g * npad + (size_t)b * SZ;
    for (int i = tid; i < SZ; i += bs) P[off + i] = acc[i];
}

__global__ __launch_bounds__(1024) void gcn_gather(const unsigned* __restrict__ sorted,
                                                   const unsigned* __restrict__ S,
                                                   const float* __restrict__ src,
                                                   float* __restrict__ P, int npad, int e,
                                                   int gpb) {
    __shared__ float acc[SZ];
    int b = blockIdx.x / gpb, g = blockIdx.x % gpb, tid = threadIdx.x;
    int bs = blockDim.x;
    for (int i = tid; i < SZ; i += bs) acc[i] = 0.0f;
    __syncthreads();
    int lo = S[b];
    int hi = (b + 1 < 256) ? (int)S[b + 1] : e;
    int q = (hi - lo + gpb - 1) / gpb;
    int mylo = lo + g * q, myhi = min(hi, mylo + q);
    if (mylo > myhi) mylo = myhi;
    int i0 = min((mylo + 3) & ~3, myhi);
    for (int i = mylo + tid; i < i0; i += bs) {
        unsigned p = sorted[i];
        atomicAdd(&acc[p >> ROWBITS], src[p & ROWMASK]);
    }
    int nv = (myhi - i0) >> 2;
    const uint4* sv = (const uint4*)(sorted + i0);
    int k = tid;
    if (k < nv) {
        uint4 v = sv[k];
        for (;;) {
            int k2 = k + bs;
            uint4 vn;
            bool more = k2 < nv;
            if (more) vn = sv[k2];           // prefetch: overlaps 4 gathers below
            float a = src[v.x & ROWMASK];
            float bb = src[v.y & ROWMASK];
            float cc = src[v.z & ROWMASK];
            float dd = src[v.w & ROWMASK];
            atomicAdd(&acc[v.x >> ROWBITS], a);
            atomicAdd(&acc[v.y >> ROWBITS], bb);
            atomicAdd(&acc[v.z >> ROWBITS], cc);
            atomicAdd(&acc[v.w >> ROWBITS], dd);
            if (!more) break;
            v = vn; k = k2;
        }
    }
    for (int i = i0 + (nv << 2) + tid; i < myhi; i += bs) {
        unsigned p = sorted[i];
        atomicAdd(&acc[p >> ROWBITS], src[p & ROWMASK]);
    }
    __syncthreads();
    size_t off = (size_t)g * npad + (size_t)b * SZ;
    for (int i = tid; i < SZ; i += bs) P[off + i] = acc[i];
}

// ---------- node-parallel combines (sum gpb partials) ----------
__global__ __launch_bounds__(256) void gcn_comb0(const float* __restrict__ P, int npad,
                                                 const float* __restrict__ x,
                                                 float* __restrict__ dinv,
                                                 float* __restrict__ xd, int n, int gpb) {
    int i = blockIdx.x * 256 + threadIdx.x;
    if (i < n) {
        float s = 1.0f;
        for (int g = 0; g < gpb; ++g) s += P[(size_t)g * npad + i];
        float d = rsqrtf(s);
        dinv[i] = d;
        xd[i] = d * x[i];
    }
}

__global__ __launch_bounds__(256) void gcn_comb1(const float* __restrict__ P, int npad,
                                                 const float* __restrict__ dinv,
                                                 float* __restrict__ xd,   // in: xd, out: td
                                                 const float* __restrict__ W1,
                                                 const float* __restrict__ b1,
                                                 const float* __restrict__ W2, int n, int gpb) {
    int i = blockIdx.x * 256 + threadIdx.x;
    if (i < n) {
        float d = dinv[i];
        float s = xd[i];
        for (int g = 0; g < gpb; ++g) s += P[(size_t)g * npad + i];
        float Sv = d * s;
        float t = 0.0f;
        #pragma unroll
        for (int f = 0; f < 10; ++f) {
            float h = fmaf(W1[f], Sv, b1[f]);
            h = h > 0.0f ? h : 0.0f;
            t = fmaf(h, W2[f], t);
        }
        xd[i] = d * t;
    }
}

__global__ __launch_bounds__(256) void gcn_comb2(const float* __restrict__ P, int npad,
                                                 const float* __restrict__ dinv,
                                                 const float* __restrict__ td,
                                                 const float* __restrict__ b2,
                                                 float* __restrict__ out, int n, int gpb) {
    int i = blockIdx.x * 256 + threadIdx.x;
    if (i < n) {
        float s = td[i];
        for (int g = 0; g < gpb; ++g) s += P[(size_t)g * npad + i];
        float y = b2[0] + dinv[i] * s;
        out[i] = fminf(fmaxf(y, -0.5f), 9.5f);
    }
}

// ---------------- fallback path (R3, passing) ----------------
__global__ void gcn_init(float* deg, float* acc1, float* acc2, int n) {
    int i = blockIdx.x * blockDim.x + threadIdx.x;
    if (i < n) { deg[i] = 1.0f; acc1[i] = 0.0f; acc2[i] = 0.0f; }
}
__global__ void gcn_deg(const int* col, float* deg, int e) {
    int i = blockIdx.x * blockDim.x + threadIdx.x;
    if (i < e) atomicAdd(&deg[col[i]], 1.0f);
}
__global__ void gcn_dinv(const float* x, float* deg_dinv, float* xd, int n) {
    int i = blockIdx.x * blockDim.x + threadIdx.x;
    if (i < n) { float d = rsqrtf(deg_dinv[i]); deg_dinv[i] = d; xd[i] = d * x[i]; }
}
__global__ void gcn_scatter(const int* row, const int* col, const float* v, float* acc, int e) {
    int i = blockIdx.x * blockDim.x + threadIdx.x;
    if (i < e) atomicAdd(&acc[col[i]], v[row[i]]);
}
__global__ void gcn_mid(const float* dinv, const float* xd, float* acc1_td,
                        const float* W1, const float* b1, const float* W2, int n) {
    int i = blockIdx.x * blockDim.x + threadIdx.x;
    if (i < n) {
        float d = dinv[i];
        float Sv = d * (acc1_td[i] + xd[i]);
        float t = 0.0f;
        #pragma unroll
        for (int f = 0; f < 10; ++f) {
            float h = fmaf(W1[f], Sv, b1[f]);
            h = h > 0.0f ? h : 0.0f;
            t = fmaf(h, W2[f], t);
        }
        acc1_td[i] = d * t;
    }
}
__global__ void gcn_final(const float* dinv, const float* td, const float* b2,
                          float* out_acc2, int n) {
    int i = blockIdx.x * blockDim.x + threadIdx.x;
    if (i < n) {
        float y = b2[0] + dinv[i] * (out_acc2[i] + td[i]);
        out_acc2[i] = fminf(fmaxf(y, -0.5f), 9.5f);
    }
}

extern "C" void kernel_launch(void* const* d_in, const int* in_sizes, int n_in,
                              void* d_out, int out_size, void* d_ws, size_t ws_size,
                              hipStream_t stream) {
    const float* x  = (const float*)d_in[0];
    const int*   ei = (const int*)d_in[1];     // int32 per harness convention
    const float* W1 = (const float*)d_in[2];
    const float* b1 = (const float*)d_in[3];
    const float* W2 = (const float*)d_in[4];
    const float* b2 = (const float*)d_in[5];

    const int n = in_sizes[0];
    const int e = in_sizes[1] / 2;
    const int* row = ei;
    const int* col = ei + e;
    float* out = (float*)d_out;

    const int nb = (n + SZ - 1) / SZ;           // buckets (245)
    const int C  = (e + CHUNK - 1) / CHUNK;     // chunks (1954)
    const int npad = nb * SZ;

    // ws: sorted u32[e] | dinv f32[n] | xd f32[n] | P f32[gpb*npad] (H aliases) | T[256] S[256]
    size_t base = (size_t)4 * e + (size_t)8 * n + 4096;
    size_t need2 = base + (size_t)8 * npad;     // proven fits (R5/R6)
    size_t need4 = base + (size_t)16 * npad;
    bool hFits = (size_t)C * 256 <= (size_t)2 * npad;

    int gpb = 0;
    if (ws_size >= need4) gpb = 4;
    else if (ws_size >= need2) gpb = 2;

    if (gpb && nb <= 256 && (unsigned)n <= ROWMASK && hFits) {
        unsigned* sorted = (unsigned*)d_ws;
        float*    dinv   = (float*)(sorted + e);
        float*    xd     = dinv + n;
        float*    P      = xd + n;              // gpb*npad floats
        unsigned* H      = (unsigned*)P;        // lifetime ends at reorder
        unsigned* T      = (unsigned*)(P + (size_t)gpb * npad);
        unsigned* S      = T + 256;

        const int gn = (n + 255) / 256;
        const int cb = (gpb == 4) ? 512 : 1024; // consume block size
        const int cg = nb * gpb;                // consume grid

        gcn_hist   <<<C,   256, 0, stream>>>(col, H, e);
        gcn_scan1  <<<256, 256, 0, stream>>>(H, T, C);
        gcn_scan2  <<<1,   256, 0, stream>>>(T, S);
        gcn_reorder<<<C,   512, 0, stream>>>(row, col, H, S, sorted, e);
        gcn_count  <<<cg,  cb,  0, stream>>>(sorted, S, P, npad, e, gpb);
        gcn_comb0  <<<gn,  256, 0, stream>>>(P, npad, x, dinv, xd, n, gpb);
        gcn_gather <<<cg,  cb,  0, stream>>>(sorted, S, xd, P, npad, e, gpb);
        gcn_comb1  <<<gn,  256, 0, stream>>>(P, npad, dinv, xd, W1, b1, W2, n, gpb);
        gcn_gather <<<cg,  cb,  0, stream>>>(sorted, S, xd, P, npad, e, gpb);
        gcn_comb2  <<<gn,  256, 0, stream>>>(P, npad, dinv, xd, b2, out, n, gpb);
    } else {
        float* deg_dinv = (float*)d_ws;
        float* xd       = deg_dinv + n;
        float* acc1     = deg_dinv + 2 * (size_t)n;
        const int B = 256;
        const int gn = (n + B - 1) / B;
        const int ge = (e + B - 1) / B;
        gcn_init   <<<gn, B, 0, stream>>>(deg_dinv, acc1, out, n);
        gcn_deg    <<<ge, B, 0, stream>>>(col, deg_dinv, e);
        gcn_dinv   <<<gn, B, 0, stream>>>(x, deg_dinv, xd, n);
        gcn_scatter<<<ge, B, 0, stream>>>(row, col, xd, acc1, e);
        gcn_mid    <<<gn, B, 0, stream>>>(deg_dinv, xd, acc1, W1, b1, W2, n);
        gcn_scatter<<<ge, B, 0, stream>>>(row, col, acc1, out, e);
        gcn_final  <<<gn, B, 0, stream>>>(deg_dinv, acc1, b2, out, n);
    }
}